// Round 4
// baseline (209.227 us; speedup 1.0000x reference)
//
#include <hip/hip_runtime.h>
#include <hip/hip_bf16.h>

// B=4, C=256, C8=32 (=Dn), H=W=64, N=4096. fp32 I/O; bf16 internal.
#define Bn 4
#define Cn 256
#define Dn 32
#define Nn 4096

typedef __bf16 bf16x8 __attribute__((ext_vector_type(8)));
typedef float f32x4 __attribute__((ext_vector_type(4)));

__device__ __forceinline__ float bf2f(unsigned short u) {
  unsigned int v = ((unsigned int)u) << 16;
  return __builtin_bit_cast(float, v);
}
__device__ __forceinline__ unsigned short f2bf(float f) {
  unsigned int v = __builtin_bit_cast(unsigned int, f);
  v += 0x7FFFu + ((v >> 16) & 1u);  // RNE
  return (unsigned short)(v >> 16);
}
// hardware packed cvt: 2 fp32 -> 2 bf16 (v_cvt_pk_bf16_f32)
__device__ __forceinline__ unsigned int pk2(float a, float b) {
  union { __hip_bfloat162 h; unsigned int u; } x;
  x.h = __float22bfloat162_rn(make_float2(a, b));
  return x.u;
}
__device__ __forceinline__ bf16x8 ldfrag(const unsigned short* p) {
  return __builtin_bit_cast(bf16x8, *(const uint4*)p);
}
__device__ __forceinline__ bf16x8 ldfrag_f32(const float* p) {
  float4 a = *(const float4*)p;
  float4 b = *(const float4*)(p + 4);
  union { unsigned int u2[4]; bf16x8 v; } x;
  x.u2[0] = pk2(a.x, a.y); x.u2[1] = pk2(a.z, a.w);
  x.u2[2] = pk2(b.x, b.y); x.u2[3] = pk2(b.z, b.w);
  return x.v;
}
// async global->LDS, 16 B per lane (lds dest = wave-uniform base + lane*16)
__device__ __forceinline__ void async16(unsigned short* lds, const unsigned short* g) {
  __builtin_amdgcn_global_load_lds(
      (const __attribute__((address_space(1))) unsigned int*)g,
      (__attribute__((address_space(3))) unsigned int*)lds, 16, 0, 0);
}

// ---------------------------------------------------------------------------
// Kernel 1: qkprep v2. Blocks 0..511: LDS-free Q/K proj GEMM (unchanged).
// Blocks 512..1023: V projection V = Wv*pre + bv -> VBf bf16, layout
// [b][c][j] (identical to old preBf, so flash is unchanged).  Bias folds
// exactly: after 1/l normalization softmax rows sum to 1.
// Qt scaled by log2(e) so flash softmax uses raw exp2.
// ---------------------------------------------------------------------------
__global__ __launch_bounds__(256) void qkprep(
    const float* __restrict__ pre, const float* __restrict__ post,
    const float* __restrict__ Wq, const float* __restrict__ bq,
    const float* __restrict__ Wk, const float* __restrict__ bk,
    const float* __restrict__ Wv, const float* __restrict__ bv,
    unsigned short* __restrict__ Qt, unsigned short* __restrict__ Kt,
    unsigned short* __restrict__ VBf)
{
  const int blk = blockIdx.x, tid = threadIdx.x;
  const int lane = tid & 63, w = tid >> 6;
  const int quad = lane >> 4, n16 = lane & 15;
  const f32x4 zz = {0.f, 0.f, 0.f, 0.f};

  if (blk >= 512) {
    // ---- V = Wv*pre + bv : 512 blocks = 4b x 128 j-tiles(32) ----
    const int vb = blk - 512;
    const int b = vb >> 7;
    const int j0 = (vb & 127) << 5;
    const int jsub = w & 1, chalf = w >> 1;   // wave: 16 j x 128 c
    const int j = j0 + jsub * 16 + n16;

    f32x4 acc[8];
#pragma unroll
    for (int ct = 0; ct < 8; ct++) acc[ct] = zz;

    const float* preB = pre + (size_t)b * Cn * Nn + j;
#pragma unroll
    for (int kc = 0; kc < 8; kc++) {
      const float* pr = preB + (size_t)(kc * 32 + quad * 8) * Nn;
      union { unsigned int u2[4]; bf16x8 v; } bp;
#pragma unroll
      for (int e2 = 0; e2 < 4; e2++) {
        float r0 = pr[(size_t)(2 * e2) * Nn], r1 = pr[(size_t)(2 * e2 + 1) * Nn];
        bp.u2[e2] = pk2(r0, r1);
      }
#pragma unroll
      for (int ct = 0; ct < 8; ct++) {
        bf16x8 aw = ldfrag_f32(Wv + (size_t)(chalf * 128 + ct * 16 + n16) * Cn + kc * 32 + quad * 8);
        acc[ct] = __builtin_amdgcn_mfma_f32_16x16x32_bf16(aw, bp.v, acc[ct], 0, 0, 0);
      }
    }
#pragma unroll
    for (int ct = 0; ct < 8; ct++) {
#pragma unroll
      for (int r = 0; r < 4; r++) {
        const int c = chalf * 128 + ct * 16 + quad * 4 + r;
        VBf[((size_t)b * Cn + c) * Nn + j] = f2bf(acc[ct][r] + bv[c]);
      }
    }
    return;
  }

  // ---- Q/K projections (unchanged) ----
  const int b = blk >> 7;
  const int i0 = (blk & 127) << 5;
  const int isub = w & 1, dh = w >> 1;
  const int i = i0 + isub * 16 + n16;

  f32x4 aq = zz, ak = zz;
  const float* postB = post + (size_t)b * Cn * Nn + i;
  const float* preB  = pre  + (size_t)b * Cn * Nn + i;

#pragma unroll
  for (int kc = 0; kc < 8; kc++) {
    const int c0 = kc * 32 + quad * 8;
    const float* pp = postB + (size_t)c0 * Nn;
    const float* pr = preB + (size_t)c0 * Nn;
    union { unsigned int u2[4]; bf16x8 v; } bp, bq8;
#pragma unroll
    for (int e2 = 0; e2 < 4; e2++) {
      float p0 = pp[(size_t)(2 * e2) * Nn], p1 = pp[(size_t)(2 * e2 + 1) * Nn];
      float r0 = pr[(size_t)(2 * e2) * Nn], r1 = pr[(size_t)(2 * e2 + 1) * Nn];
      bp.u2[e2] = pk2(p0, p1);
      bq8.u2[e2] = pk2(r0, r1);
    }
    bf16x8 awq = ldfrag_f32(Wq + (size_t)(dh * 16 + n16) * Cn + kc * 32 + quad * 8);
    bf16x8 awk = ldfrag_f32(Wk + (size_t)(dh * 16 + n16) * Cn + kc * 32 + quad * 8);
    aq = __builtin_amdgcn_mfma_f32_16x16x32_bf16(awq, bp.v, aq, 0, 0, 0);
    ak = __builtin_amdgcn_mfma_f32_16x16x32_bf16(awk, bq8.v, ak, 0, 0, 0);
  }
  const float LOG2E = 1.44269504f;
  union { unsigned short s[4]; uint2 u; } oq, ok;
#pragma unroll
  for (int r = 0; r < 4; r++) {
    int d = dh * 16 + quad * 4 + r;
    oq.s[r] = f2bf((aq[r] + bq[d]) * LOG2E);
    ok.s[r] = f2bf(ak[r] + bk[d]);
  }
  *(uint2*)(Qt + ((size_t)b * Nn + i) * Dn + dh * 16 + quad * 4) = oq.u;
  *(uint2*)(Kt + ((size_t)b * Nn + i) * Dn + dh * 16 + quad * 4) = ok.u;
}

// ---------------------------------------------------------------------------
// Kernel 2: flash attention v9 (unchanged from R3, reads VBf instead of
// preBf). Async global_load_lds V staging single-buffered, DMA covered by
// S^T/softmax phase; Pl 64-stride XOR-swizzled; LDS 40960 -> 4 blocks/CU.
// Grid 1024 = 4b x 64 it(64 i) x 4 js; 256 thr = 4 waves.
// ---------------------------------------------------------------------------
__global__ __launch_bounds__(256, 4) void flash_attn(
    const unsigned short* __restrict__ Qt, const unsigned short* __restrict__ Kt,
    const unsigned short* __restrict__ VBf,
    unsigned short* __restrict__ Opart, float* __restrict__ Lpart)
{
  __shared__ __align__(16) unsigned short sX[256 * 64];  // 32 KB
  __shared__ __align__(16) unsigned short Pl[64 * 64];   // 8 KB (swizzled)

  const int tid = threadIdx.x;
  const int lane = tid & 63, w = tid >> 6;
  const int quad = lane >> 4, n16 = lane & 15;
  const int b = blockIdx.x >> 8;
  const int js = (blockIdx.x >> 6) & 3;
  const int it = blockIdx.x & 63;
  const int i0 = it * 64;
  const int jbase = js * 1024;

  // Q B-frag for wave's own 16-i subtile (S^T: B n=i, k=d)
  const bf16x8 qf = ldfrag(Qt + ((size_t)b * Nn + i0 + w * 16 + n16) * Dn + quad * 8);

  const f32x4 zz = {0.f, 0.f, 0.f, 0.f};
  f32x4 acc[4][4];                       // [i-sub][c-tile within wave's 64 c]
#pragma unroll
  for (int sub = 0; sub < 4; sub++)
#pragma unroll
    for (int ct = 0; ct < 4; ct++) acc[sub][ct] = zz;
  float lrow = 0.f;                      // softmax denom, col i = n16 (dup x4)

  const size_t laneoff = (size_t)(lane >> 3) * Nn + (size_t)(((lane & 7) ^ (lane >> 3)) << 3);
  const unsigned short* preB = VBf + (size_t)b * Cn * Nn + laneoff;
  const int xsw = n16 & 7;
  const int xoff0 = (quad ^ xsw) << 3;
  const int xoff1 = ((4 + quad) ^ xsw) << 3;
  const int psw = (n16 & 7) << 3;        // Pl XOR swizzle (16B units per 8 rows)

  for (int t = 0; t < 16; ++t) {
    const int j0 = jbase + t * 64;
    __syncthreads();                     // sX(t-1)/Pl(t-1) fully consumed
    // async stage V tile 256c x 64j (XOR col swizzle), 8 x 16B per lane
#pragma unroll
    for (int k = 0; k < 8; k++) {
      const int rb = (k * 4 + w) * 8;
      async16(sX + rb * 64 + (lane << 3), preB + (size_t)rb * Nn + j0);
    }
    // S^T = K Q^T for wave's 16 i; K b128 direct from L2-resident Kt
    {
      f32x4 sc[4];
#pragma unroll
      for (int jt = 0; jt < 4; jt++) {
        bf16x8 akf = ldfrag(Kt + ((size_t)b * Nn + j0 + jt * 16 + n16) * Dn + quad * 8);
        sc[jt] = __builtin_amdgcn_mfma_f32_16x16x32_bf16(akf, qf, zz, 0, 0, 0);
      }
      float ps = 0.f;
#pragma unroll
      for (int jt = 0; jt < 4; jt++) {
        float p0 = exp2f(fminf(sc[jt][0], 101.f));
        float p1 = exp2f(fminf(sc[jt][1], 101.f));
        float p2 = exp2f(fminf(sc[jt][2], 101.f));
        float p3 = exp2f(fminf(sc[jt][3], 101.f));
        ps += (p0 + p1) + (p2 + p3);
        union { unsigned int u2[2]; uint2 u; } pk;
        pk.u2[0] = pk2(p0, p1);
        pk.u2[1] = pk2(p2, p3);
        // Pl[i][j], i = w*16+n16, j = jt*16+quad*4..+3 (XOR-swizzled cols)
        *(uint2*)&Pl[(size_t)(w * 16 + n16) * 64 + ((jt * 16 + quad * 4) ^ psw)] = pk.u;
      }
      ps += __shfl_xor(ps, 16);
      ps += __shfl_xor(ps, 32);
      lrow += ps;
    }
    __syncthreads();                     // DMA drained + Pl visible

    // PV(t): U[c][i] += V[c][j] P^T[j][i], 16x16x32 (k = 32 j)
#pragma unroll
    for (int kc = 0; kc < 2; kc++) {
      const int xo = kc ? xoff1 : xoff0;
      bf16x8 pB[4];
#pragma unroll
      for (int sub = 0; sub < 4; sub++)
        pB[sub] = ldfrag(&Pl[(size_t)(sub * 16 + n16) * 64 + ((kc * 32 + quad * 8) ^ psw)]);
#pragma unroll
      for (int ct = 0; ct < 4; ct++) {
        const int crow = w * 64 + ct * 16 + n16;
        bf16x8 av = ldfrag(&sX[crow * 64 + xo]);
        acc[0][ct] = __builtin_amdgcn_mfma_f32_16x16x32_bf16(av, pB[0], acc[0][ct], 0, 0, 0);
        acc[1][ct] = __builtin_amdgcn_mfma_f32_16x16x32_bf16(av, pB[1], acc[1][ct], 0, 0, 0);
        acc[2][ct] = __builtin_amdgcn_mfma_f32_16x16x32_bf16(av, pB[2], acc[2][ct], 0, 0, 0);
        acc[3][ct] = __builtin_amdgcn_mfma_f32_16x16x32_bf16(av, pB[3], acc[3][ct], 0, 0, 0);
      }
    }
  }

  // partial store: O bf16 [js*4+b][i][c], l fp32 [js*4+b][i]
  const size_t pbase = (size_t)(js * 4 + b) * Nn;
  if (quad == 0) Lpart[pbase + i0 + w * 16 + n16] = lrow;
#pragma unroll
  for (int sub = 0; sub < 4; sub++) {
    const int i = i0 + sub * 16 + n16;
#pragma unroll
    for (int ct = 0; ct < 4; ct++) {
      union { unsigned int u2[2]; uint2 u; } pk;
      pk.u2[0] = pk2(acc[sub][ct][0], acc[sub][ct][1]);
      pk.u2[1] = pk2(acc[sub][ct][2], acc[sub][ct][3]);
      *(uint2*)(Opart + (pbase + i) * 256 + w * 64 + ct * 16 + quad * 4) = pk.u;
    }
  }
}

// ---------------------------------------------------------------------------
// Kernel 3: combine v2 — pure streaming merge (no GEMM; Wv applied in
// qkprep). out[b][c][i] = g * (sum_js O[js][i][c]) / l[i] + post[b][c][i].
// Grid 1024 = 4b x 64 i-tiles(64) x 4 c-tiles(64); 256 thr.
// LDS stride-65 fp32 transpose tile: both phases <=2-way bank aliasing
// (free); LDS ops scalar b32 (LDS BW is not the limit here).
// ---------------------------------------------------------------------------
__global__ __launch_bounds__(256) void combine(
    const unsigned short* __restrict__ Opart, const float* __restrict__ Lpart,
    const float* __restrict__ post, const float* __restrict__ gamma,
    float* __restrict__ out)
{
  __shared__ float sT[64 * 65];   // [c][i], stride 65
  __shared__ float sL[64];

  const int tid = threadIdx.x;
  const int b = blockIdx.x >> 8;
  const int rest = blockIdx.x & 255;
  const int i0 = (rest >> 2) * 64;
  const int c0 = (rest & 3) * 64;

  if (tid < 64) {
    float l = 0.f;
#pragma unroll
    for (int js = 0; js < 4; js++) l += Lpart[(size_t)(js * 4 + b) * Nn + i0 + tid];
    sL[tid] = 1.f / l;
  }
  __syncthreads();

  // accumulate 4 partials, normalize, write transposed into sT
#pragma unroll
  for (int pass = 0; pass < 2; pass++) {
    const int il = (tid >> 3) + pass * 32;   // 0..63
    const int c8 = (tid & 7) << 3;           // 0..56
    float a[8] = {0.f, 0.f, 0.f, 0.f, 0.f, 0.f, 0.f, 0.f};
#pragma unroll
    for (int js = 0; js < 4; js++) {
      uint4 uu = *(const uint4*)(Opart + ((size_t)(js * 4 + b) * Nn + i0 + il) * 256 + c0 + c8);
      const unsigned short* us = (const unsigned short*)&uu;
#pragma unroll
      for (int e = 0; e < 8; e++) a[e] += bf2f(us[e]);
    }
    const float inv = sL[il];
#pragma unroll
    for (int e = 0; e < 8; e++) sT[(c8 + e) * 65 + il] = a[e] * inv;
  }
  __syncthreads();

  const float g = gamma[0];
#pragma unroll
  for (int itr = 0; itr < 4; itr++) {
    const int slot = tid + itr * 256;        // 1024 = 64 c x 16 i-quads
    const int cr = slot >> 4, i4 = (slot & 15) << 2;
    const size_t addr = ((size_t)b * Cn + c0 + cr) * Nn + i0 + i4;
    float4 pp = *(const float4*)(post + addr);
    float4 ov;
    ov.x = g * sT[cr * 65 + i4 + 0] + pp.x;
    ov.y = g * sT[cr * 65 + i4 + 1] + pp.y;
    ov.z = g * sT[cr * 65 + i4 + 2] + pp.z;
    ov.w = g * sT[cr * 65 + i4 + 3] + pp.w;
    *(float4*)(out + addr) = ov;
  }
}

extern "C" void kernel_launch(void* const* d_in, const int* in_sizes, int n_in,
                              void* d_out, int out_size, void* d_ws, size_t ws_size,
                              hipStream_t stream) {
  const float* pre   = (const float*)d_in[0];
  const float* post  = (const float*)d_in[1];
  const float* Wq    = (const float*)d_in[2];
  const float* bq    = (const float*)d_in[3];
  const float* Wk    = (const float*)d_in[4];
  const float* bk    = (const float*)d_in[5];
  const float* Wv    = (const float*)d_in[6];
  const float* bv    = (const float*)d_in[7];
  const float* gamma = (const float*)d_in[8];
  float* out = (float*)d_out;

  unsigned short* ws = (unsigned short*)d_ws;
  unsigned short* Qt    = ws;                                   // 512K sh
  unsigned short* Kt    = Qt + (size_t)Bn * Nn * Dn;            // 512K sh
  unsigned short* VBf   = Kt + (size_t)Bn * Nn * Dn;            // 4M sh
  float* Lpart = (float*)(VBf + (size_t)Bn * Cn * Nn);          // 64K fl
  unsigned short* Opart = (unsigned short*)(Lpart + 4 * Bn * Nn);  // 16.7M sh

  qkprep<<<1024, 256, 0, stream>>>(pre, post, Wq, bq, Wk, bk, Wv, bv,
                                   Qt, Kt, VBf);
  flash_attn<<<1024, 256, 0, stream>>>(Qt, Kt, VBf, Opart, Lpart);
  combine<<<1024, 256, 0, stream>>>(Opart, Lpart, post, gamma, out);
}

// Round 5
// 208.922 us; speedup vs baseline: 1.0015x; 1.0015x over previous
//
#include <hip/hip_runtime.h>
#include <hip/hip_bf16.h>

// B=4, C=256, C8=32 (=Dn), H=W=64, N=4096. fp32 I/O; bf16 internal.
#define Bn 4
#define Cn 256
#define Dn 32
#define Nn 4096

typedef __bf16 bf16x8 __attribute__((ext_vector_type(8)));
typedef float f32x4 __attribute__((ext_vector_type(4)));

__device__ __forceinline__ float bf2f(unsigned short u) {
  unsigned int v = ((unsigned int)u) << 16;
  return __builtin_bit_cast(float, v);
}
__device__ __forceinline__ unsigned short f2bf(float f) {
  unsigned int v = __builtin_bit_cast(unsigned int, f);
  v += 0x7FFFu + ((v >> 16) & 1u);  // RNE
  return (unsigned short)(v >> 16);
}
// hardware packed cvt: 2 fp32 -> 2 bf16 (v_cvt_pk_bf16_f32)
__device__ __forceinline__ unsigned int pk2(float a, float b) {
  union { __hip_bfloat162 h; unsigned int u; } x;
  x.h = __float22bfloat162_rn(make_float2(a, b));
  return x.u;
}
__device__ __forceinline__ bf16x8 ldfrag(const unsigned short* p) {
  return __builtin_bit_cast(bf16x8, *(const uint4*)p);
}
__device__ __forceinline__ bf16x8 ldfrag_f32(const float* p) {
  float4 a = *(const float4*)p;
  float4 b = *(const float4*)(p + 4);
  union { unsigned int u2[4]; bf16x8 v; } x;
  x.u2[0] = pk2(a.x, a.y); x.u2[1] = pk2(a.z, a.w);
  x.u2[2] = pk2(b.x, b.y); x.u2[3] = pk2(b.z, b.w);
  return x.v;
}
// async global->LDS, 16 B per lane (lds dest = wave-uniform base + lane*16)
__device__ __forceinline__ void async16(unsigned short* lds, const unsigned short* g) {
  __builtin_amdgcn_global_load_lds(
      (const __attribute__((address_space(1))) unsigned int*)g,
      (__attribute__((address_space(3))) unsigned int*)lds, 16, 0, 0);
}

// ---------------------------------------------------------------------------
// Kernel 1: qkprep v3. Blocks 0..511: LDS-free Q/K proj GEMM (unchanged).
// Blocks 512..1023: V = Wv*pre + bv -> VBf bf16 [b][c][j]; epilogue staged
// through LDS sV[256][40] (pad 8 j: row starts 16B-aligned, ds_write quad
// aliasing 2-way = free) so global stores are coalesced uint4 row copies
// instead of 2B scatters (the R4 regression).
// Qt scaled by log2(e) so flash softmax uses raw exp2.
// ---------------------------------------------------------------------------
__global__ __launch_bounds__(256) void qkprep(
    const float* __restrict__ pre, const float* __restrict__ post,
    const float* __restrict__ Wq, const float* __restrict__ bq,
    const float* __restrict__ Wk, const float* __restrict__ bk,
    const float* __restrict__ Wv, const float* __restrict__ bv,
    unsigned short* __restrict__ Qt, unsigned short* __restrict__ Kt,
    unsigned short* __restrict__ VBf)
{
  const int blk = blockIdx.x, tid = threadIdx.x;
  const int lane = tid & 63, w = tid >> 6;
  const int quad = lane >> 4, n16 = lane & 15;
  const f32x4 zz = {0.f, 0.f, 0.f, 0.f};

  if (blk >= 512) {
    // ---- V = Wv*pre + bv : 512 blocks = 4b x 128 j-tiles(32) ----
    __shared__ __align__(16) unsigned short sV[256 * 40];  // 20 KB
    const int vb = blk - 512;
    const int b = vb >> 7;
    const int j0 = (vb & 127) << 5;
    const int jsub = w & 1, chalf = w >> 1;   // wave: 16 j x 128 c
    const int j = j0 + jsub * 16 + n16;

    f32x4 acc[8];
#pragma unroll
    for (int ct = 0; ct < 8; ct++) acc[ct] = zz;

    const float* preB = pre + (size_t)b * Cn * Nn + j;
#pragma unroll
    for (int kc = 0; kc < 8; kc++) {
      const float* pr = preB + (size_t)(kc * 32 + quad * 8) * Nn;
      union { unsigned int u2[4]; bf16x8 v; } bp;
#pragma unroll
      for (int e2 = 0; e2 < 4; e2++) {
        float r0 = pr[(size_t)(2 * e2) * Nn], r1 = pr[(size_t)(2 * e2 + 1) * Nn];
        bp.u2[e2] = pk2(r0, r1);
      }
#pragma unroll
      for (int ct = 0; ct < 8; ct++) {
        bf16x8 aw = ldfrag_f32(Wv + (size_t)(chalf * 128 + ct * 16 + n16) * Cn + kc * 32 + quad * 8);
        acc[ct] = __builtin_amdgcn_mfma_f32_16x16x32_bf16(aw, bp.v, acc[ct], 0, 0, 0);
      }
    }
    // epilogue: bias + bf16 into LDS [c][j-padded], then coalesced row copy
#pragma unroll
    for (int ct = 0; ct < 8; ct++) {
#pragma unroll
      for (int r = 0; r < 4; r++) {
        const int c = chalf * 128 + ct * 16 + quad * 4 + r;
        sV[c * 40 + jsub * 16 + n16] = f2bf(acc[ct][r] + bv[c]);
      }
    }
    __syncthreads();
#pragma unroll
    for (int k = 0; k < 4; k++) {
      const int slot = tid + k * 256;          // 1024 = 256 c x 4 j-octets
      const int c = slot >> 2, seg = slot & 3;
      *(uint4*)(VBf + ((size_t)b * Cn + c) * Nn + j0 + seg * 8) =
          *(const uint4*)(sV + c * 40 + seg * 8);
    }
    return;
  }

  // ---- Q/K projections (unchanged) ----
  const int b = blk >> 7;
  const int i0 = (blk & 127) << 5;
  const int isub = w & 1, dh = w >> 1;
  const int i = i0 + isub * 16 + n16;

  f32x4 aq = zz, ak = zz;
  const float* postB = post + (size_t)b * Cn * Nn + i;
  const float* preB  = pre  + (size_t)b * Cn * Nn + i;

#pragma unroll
  for (int kc = 0; kc < 8; kc++) {
    const int c0 = kc * 32 + quad * 8;
    const float* pp = postB + (size_t)c0 * Nn;
    const float* pr = preB + (size_t)c0 * Nn;
    union { unsigned int u2[4]; bf16x8 v; } bp, bq8;
#pragma unroll
    for (int e2 = 0; e2 < 4; e2++) {
      float p0 = pp[(size_t)(2 * e2) * Nn], p1 = pp[(size_t)(2 * e2 + 1) * Nn];
      float r0 = pr[(size_t)(2 * e2) * Nn], r1 = pr[(size_t)(2 * e2 + 1) * Nn];
      bp.u2[e2] = pk2(p0, p1);
      bq8.u2[e2] = pk2(r0, r1);
    }
    bf16x8 awq = ldfrag_f32(Wq + (size_t)(dh * 16 + n16) * Cn + kc * 32 + quad * 8);
    bf16x8 awk = ldfrag_f32(Wk + (size_t)(dh * 16 + n16) * Cn + kc * 32 + quad * 8);
    aq = __builtin_amdgcn_mfma_f32_16x16x32_bf16(awq, bp.v, aq, 0, 0, 0);
    ak = __builtin_amdgcn_mfma_f32_16x16x32_bf16(awk, bq8.v, ak, 0, 0, 0);
  }
  const float LOG2E = 1.44269504f;
  union { unsigned short s[4]; uint2 u; } oq, ok;
#pragma unroll
  for (int r = 0; r < 4; r++) {
    int d = dh * 16 + quad * 4 + r;
    oq.s[r] = f2bf((aq[r] + bq[d]) * LOG2E);
    ok.s[r] = f2bf(ak[r] + bk[d]);
  }
  *(uint2*)(Qt + ((size_t)b * Nn + i) * Dn + dh * 16 + quad * 4) = oq.u;
  *(uint2*)(Kt + ((size_t)b * Nn + i) * Dn + dh * 16 + quad * 4) = ok.u;
}

// ---------------------------------------------------------------------------
// Kernel 2: flash attention v9 (unchanged). Async global_load_lds V
// staging single-buffered, DMA covered by S^T/softmax phase; Pl 64-stride
// XOR-swizzled; LDS 40960 -> 4 blocks/CU.
// Grid 1024 = 4b x 64 it(64 i) x 4 js; 256 thr = 4 waves.
// ---------------------------------------------------------------------------
__global__ __launch_bounds__(256, 4) void flash_attn(
    const unsigned short* __restrict__ Qt, const unsigned short* __restrict__ Kt,
    const unsigned short* __restrict__ VBf,
    unsigned short* __restrict__ Opart, float* __restrict__ Lpart)
{
  __shared__ __align__(16) unsigned short sX[256 * 64];  // 32 KB
  __shared__ __align__(16) unsigned short Pl[64 * 64];   // 8 KB (swizzled)

  const int tid = threadIdx.x;
  const int lane = tid & 63, w = tid >> 6;
  const int quad = lane >> 4, n16 = lane & 15;
  const int b = blockIdx.x >> 8;
  const int js = (blockIdx.x >> 6) & 3;
  const int it = blockIdx.x & 63;
  const int i0 = it * 64;
  const int jbase = js * 1024;

  // Q B-frag for wave's own 16-i subtile (S^T: B n=i, k=d)
  const bf16x8 qf = ldfrag(Qt + ((size_t)b * Nn + i0 + w * 16 + n16) * Dn + quad * 8);

  const f32x4 zz = {0.f, 0.f, 0.f, 0.f};
  f32x4 acc[4][4];                       // [i-sub][c-tile within wave's 64 c]
#pragma unroll
  for (int sub = 0; sub < 4; sub++)
#pragma unroll
    for (int ct = 0; ct < 4; ct++) acc[sub][ct] = zz;
  float lrow = 0.f;                      // softmax denom, col i = n16 (dup x4)

  const size_t laneoff = (size_t)(lane >> 3) * Nn + (size_t)(((lane & 7) ^ (lane >> 3)) << 3);
  const unsigned short* preB = VBf + (size_t)b * Cn * Nn + laneoff;
  const int xsw = n16 & 7;
  const int xoff0 = (quad ^ xsw) << 3;
  const int xoff1 = ((4 + quad) ^ xsw) << 3;
  const int psw = (n16 & 7) << 3;        // Pl XOR swizzle (16B units per 8 rows)

  for (int t = 0; t < 16; ++t) {
    const int j0 = jbase + t * 64;
    __syncthreads();                     // sX(t-1)/Pl(t-1) fully consumed
    // async stage V tile 256c x 64j (XOR col swizzle), 8 x 16B per lane
#pragma unroll
    for (int k = 0; k < 8; k++) {
      const int rb = (k * 4 + w) * 8;
      async16(sX + rb * 64 + (lane << 3), preB + (size_t)rb * Nn + j0);
    }
    // S^T = K Q^T for wave's 16 i; K b128 direct from L2-resident Kt
    {
      f32x4 sc[4];
#pragma unroll
      for (int jt = 0; jt < 4; jt++) {
        bf16x8 akf = ldfrag(Kt + ((size_t)b * Nn + j0 + jt * 16 + n16) * Dn + quad * 8);
        sc[jt] = __builtin_amdgcn_mfma_f32_16x16x32_bf16(akf, qf, zz, 0, 0, 0);
      }
      float ps = 0.f;
#pragma unroll
      for (int jt = 0; jt < 4; jt++) {
        float p0 = exp2f(fminf(sc[jt][0], 101.f));
        float p1 = exp2f(fminf(sc[jt][1], 101.f));
        float p2 = exp2f(fminf(sc[jt][2], 101.f));
        float p3 = exp2f(fminf(sc[jt][3], 101.f));
        ps += (p0 + p1) + (p2 + p3);
        union { unsigned int u2[2]; uint2 u; } pk;
        pk.u2[0] = pk2(p0, p1);
        pk.u2[1] = pk2(p2, p3);
        // Pl[i][j], i = w*16+n16, j = jt*16+quad*4..+3 (XOR-swizzled cols)
        *(uint2*)&Pl[(size_t)(w * 16 + n16) * 64 + ((jt * 16 + quad * 4) ^ psw)] = pk.u;
      }
      ps += __shfl_xor(ps, 16);
      ps += __shfl_xor(ps, 32);
      lrow += ps;
    }
    __syncthreads();                     // DMA drained + Pl visible

    // PV(t): U[c][i] += V[c][j] P^T[j][i], 16x16x32 (k = 32 j)
#pragma unroll
    for (int kc = 0; kc < 2; kc++) {
      const int xo = kc ? xoff1 : xoff0;
      bf16x8 pB[4];
#pragma unroll
      for (int sub = 0; sub < 4; sub++)
        pB[sub] = ldfrag(&Pl[(size_t)(sub * 16 + n16) * 64 + ((kc * 32 + quad * 8) ^ psw)]);
#pragma unroll
      for (int ct = 0; ct < 4; ct++) {
        const int crow = w * 64 + ct * 16 + n16;
        bf16x8 av = ldfrag(&sX[crow * 64 + xo]);
        acc[0][ct] = __builtin_amdgcn_mfma_f32_16x16x32_bf16(av, pB[0], acc[0][ct], 0, 0, 0);
        acc[1][ct] = __builtin_amdgcn_mfma_f32_16x16x32_bf16(av, pB[1], acc[1][ct], 0, 0, 0);
        acc[2][ct] = __builtin_amdgcn_mfma_f32_16x16x32_bf16(av, pB[2], acc[2][ct], 0, 0, 0);
        acc[3][ct] = __builtin_amdgcn_mfma_f32_16x16x32_bf16(av, pB[3], acc[3][ct], 0, 0, 0);
      }
    }
  }

  // partial store: O bf16 [js*4+b][i][c], l fp32 [js*4+b][i]
  const size_t pbase = (size_t)(js * 4 + b) * Nn;
  if (quad == 0) Lpart[pbase + i0 + w * 16 + n16] = lrow;
#pragma unroll
  for (int sub = 0; sub < 4; sub++) {
    const int i = i0 + sub * 16 + n16;
#pragma unroll
    for (int ct = 0; ct < 4; ct++) {
      union { unsigned int u2[2]; uint2 u; } pk;
      pk.u2[0] = pk2(acc[sub][ct][0], acc[sub][ct][1]);
      pk.u2[1] = pk2(acc[sub][ct][2], acc[sub][ct][3]);
      *(uint2*)(Opart + (pbase + i) * 256 + w * 64 + ct * 16 + quad * 4) = pk.u;
    }
  }
}

// ---------------------------------------------------------------------------
// Kernel 3: combine v2 — pure streaming merge (no GEMM; Wv applied in
// qkprep). out[b][c][i] = g * (sum_js O[js][i][c]) / l[i] + post[b][c][i].
// Grid 1024 = 4b x 64 i-tiles(64) x 4 c-tiles(64); 256 thr.
// ---------------------------------------------------------------------------
__global__ __launch_bounds__(256) void combine(
    const unsigned short* __restrict__ Opart, const float* __restrict__ Lpart,
    const float* __restrict__ post, const float* __restrict__ gamma,
    float* __restrict__ out)
{
  __shared__ float sT[64 * 65];   // [c][i], stride 65
  __shared__ float sL[64];

  const int tid = threadIdx.x;
  const int b = blockIdx.x >> 8;
  const int rest = blockIdx.x & 255;
  const int i0 = (rest >> 2) * 64;
  const int c0 = (rest & 3) * 64;

  if (tid < 64) {
    float l = 0.f;
#pragma unroll
    for (int js = 0; js < 4; js++) l += Lpart[(size_t)(js * 4 + b) * Nn + i0 + tid];
    sL[tid] = 1.f / l;
  }
  __syncthreads();

  // accumulate 4 partials, normalize, write transposed into sT
#pragma unroll
  for (int pass = 0; pass < 2; pass++) {
    const int il = (tid >> 3) + pass * 32;   // 0..63
    const int c8 = (tid & 7) << 3;           // 0..56
    float a[8] = {0.f, 0.f, 0.f, 0.f, 0.f, 0.f, 0.f, 0.f};
#pragma unroll
    for (int js = 0; js < 4; js++) {
      uint4 uu = *(const uint4*)(Opart + ((size_t)(js * 4 + b) * Nn + i0 + il) * 256 + c0 + c8);
      const unsigned short* us = (const unsigned short*)&uu;
#pragma unroll
      for (int e = 0; e < 8; e++) a[e] += bf2f(us[e]);
    }
    const float inv = sL[il];
#pragma unroll
    for (int e = 0; e < 8; e++) sT[(c8 + e) * 65 + il] = a[e] * inv;
  }
  __syncthreads();

  const float g = gamma[0];
#pragma unroll
  for (int itr = 0; itr < 4; itr++) {
    const int slot = tid + itr * 256;        // 1024 = 64 c x 16 i-quads
    const int cr = slot >> 4, i4 = (slot & 15) << 2;
    const size_t addr = ((size_t)b * Cn + c0 + cr) * Nn + i0 + i4;
    float4 pp = *(const float4*)(post + addr);
    float4 ov;
    ov.x = g * sT[cr * 65 + i4 + 0] + pp.x;
    ov.y = g * sT[cr * 65 + i4 + 1] + pp.y;
    ov.z = g * sT[cr * 65 + i4 + 2] + pp.z;
    ov.w = g * sT[cr * 65 + i4 + 3] + pp.w;
    *(float4*)(out + addr) = ov;
  }
}

extern "C" void kernel_launch(void* const* d_in, const int* in_sizes, int n_in,
                              void* d_out, int out_size, void* d_ws, size_t ws_size,
                              hipStream_t stream) {
  const float* pre   = (const float*)d_in[0];
  const float* post  = (const float*)d_in[1];
  const float* Wq    = (const float*)d_in[2];
  const float* bq    = (const float*)d_in[3];
  const float* Wk    = (const float*)d_in[4];
  const float* bk    = (const float*)d_in[5];
  const float* Wv    = (const float*)d_in[6];
  const float* bv    = (const float*)d_in[7];
  const float* gamma = (const float*)d_in[8];
  float* out = (float*)d_out;

  unsigned short* ws = (unsigned short*)d_ws;
  unsigned short* Qt    = ws;                                   // 512K sh
  unsigned short* Kt    = Qt + (size_t)Bn * Nn * Dn;            // 512K sh
  unsigned short* VBf   = Kt + (size_t)Bn * Nn * Dn;            // 4M sh
  float* Lpart = (float*)(VBf + (size_t)Bn * Cn * Nn);          // 64K fl
  unsigned short* Opart = (unsigned short*)(Lpart + 4 * Bn * Nn);  // 16.7M sh

  qkprep<<<1024, 256, 0, stream>>>(pre, post, Wq, bq, Wk, bk, Wv, bv,
                                   Qt, Kt, VBf);
  flash_attn<<<1024, 256, 0, stream>>>(Qt, Kt, VBf, Opart, Lpart);
  combine<<<1024, 256, 0, stream>>>(Opart, Lpart, post, gamma, out);
}

// Round 6
// 186.944 us; speedup vs baseline: 1.1192x; 1.1176x over previous
//
#include <hip/hip_runtime.h>
#include <hip/hip_bf16.h>

// B=4, C=256, C8=32 (=Dn), H=W=64, N=4096. fp32 I/O; bf16 internal.
#define Bn 4
#define Cn 256
#define Dn 32
#define Nn 4096

typedef __bf16 bf16x8 __attribute__((ext_vector_type(8)));
typedef float f32x4 __attribute__((ext_vector_type(4)));

__device__ __forceinline__ float bf2f(unsigned short u) {
  unsigned int v = ((unsigned int)u) << 16;
  return __builtin_bit_cast(float, v);
}
__device__ __forceinline__ unsigned short f2bf(float f) {
  unsigned int v = __builtin_bit_cast(unsigned int, f);
  v += 0x7FFFu + ((v >> 16) & 1u);  // RNE
  return (unsigned short)(v >> 16);
}
// hardware packed cvt: 2 fp32 -> 2 bf16 (v_cvt_pk_bf16_f32)
__device__ __forceinline__ unsigned int pk2(float a, float b) {
  union { __hip_bfloat162 h; unsigned int u; } x;
  x.h = __float22bfloat162_rn(make_float2(a, b));
  return x.u;
}
__device__ __forceinline__ bf16x8 ldfrag(const unsigned short* p) {
  return __builtin_bit_cast(bf16x8, *(const uint4*)p);
}
__device__ __forceinline__ uint4 pack8(const float* p) {
  float4 a = *(const float4*)p;
  float4 b = *(const float4*)(p + 4);
  union { unsigned int u2[4]; uint4 u; } x;
  x.u2[0] = pk2(a.x, a.y); x.u2[1] = pk2(a.z, a.w);
  x.u2[2] = pk2(b.x, b.y); x.u2[3] = pk2(b.z, b.w);
  return x.u;
}
// async global->LDS, 16 B per lane (lds dest = wave-uniform base + lane*16)
__device__ __forceinline__ void async16(unsigned short* lds, const unsigned short* g) {
  __builtin_amdgcn_global_load_lds(
      (const __attribute__((address_space(1))) unsigned int*)g,
      (__attribute__((address_space(3))) unsigned int*)lds, 16, 0, 0);
}

// ---------------------------------------------------------------------------
// Kernel 0: wconv — convert Wq/Wk/Wv fp32 -> bf16 ONCE (R4/R5 regression was
// per-block re-conversion: 256 pk2/thread in the V-GEMM). 81920 elems,
// 40 blocks x 256 thr x 8 elems.
// ---------------------------------------------------------------------------
__global__ __launch_bounds__(256) void wconv(
    const float* __restrict__ Wq, const float* __restrict__ Wk,
    const float* __restrict__ Wv,
    unsigned short* __restrict__ WqBf, unsigned short* __restrict__ WkBf,
    unsigned short* __restrict__ WvBf)
{
  const size_t base = ((size_t)blockIdx.x * 256 + threadIdx.x) * 8;
  if (base < 8192) {
    *(uint4*)(WqBf + base) = pack8(Wq + base);
  } else if (base < 16384) {
    *(uint4*)(WkBf + base - 8192) = pack8(Wk + base - 8192);
  } else {
    *(uint4*)(WvBf + base - 16384) = pack8(Wv + base - 16384);
  }
}

// ---------------------------------------------------------------------------
// Kernel 1: qkprep v4 — fused Q/K/V projections. 512 blocks = 4b x 128
// n-tiles(32). The pre B-frag (bq8) built for K is algebraically the same
// B operand V needs (same n-columns, same c-contraction), so V's 64 MFMA
// reuse it from registers: pre/post each read ONCE, weights read as bf16
// from L2 (no per-block conversion). Wave (isub,dh): Q/K for d-half dh,
// n-subtile isub + V for c-half dh*128, n-subtile isub (accv 8 x f32x4).
// V epilogue staged via sV LDS for coalesced uint4 stores.
// Qt scaled by log2(e) so flash softmax uses raw exp2.
// ---------------------------------------------------------------------------
__global__ __launch_bounds__(256) void qkprep(
    const float* __restrict__ pre, const float* __restrict__ post,
    const unsigned short* __restrict__ WqBf, const float* __restrict__ bq,
    const unsigned short* __restrict__ WkBf, const float* __restrict__ bk,
    const unsigned short* __restrict__ WvBf, const float* __restrict__ bv,
    unsigned short* __restrict__ Qt, unsigned short* __restrict__ Kt,
    unsigned short* __restrict__ VBf)
{
  __shared__ __align__(16) unsigned short sV[256 * 40];  // 20 KB

  const int tid = threadIdx.x;
  const int lane = tid & 63, w = tid >> 6;
  const int quad = lane >> 4, n16 = lane & 15;
  const int b = blockIdx.x >> 7;
  const int i0 = (blockIdx.x & 127) << 5;
  const int isub = w & 1, dh = w >> 1;
  const int i = i0 + isub * 16 + n16;

  const f32x4 zz = {0.f, 0.f, 0.f, 0.f};
  f32x4 aq = zz, ak = zz;
  f32x4 accv[8];
#pragma unroll
  for (int ct = 0; ct < 8; ct++) accv[ct] = zz;

  const float* postB = post + (size_t)b * Cn * Nn + i;
  const float* preB  = pre  + (size_t)b * Cn * Nn + i;

#pragma unroll
  for (int kc = 0; kc < 8; kc++) {
    const int c0 = kc * 32 + quad * 8;
    const float* pp = postB + (size_t)c0 * Nn;
    const float* pr = preB + (size_t)c0 * Nn;
    union { unsigned int u2[4]; bf16x8 v; } bp, bq8;
#pragma unroll
    for (int e2 = 0; e2 < 4; e2++) {
      float p0 = pp[(size_t)(2 * e2) * Nn], p1 = pp[(size_t)(2 * e2 + 1) * Nn];
      float r0 = pr[(size_t)(2 * e2) * Nn], r1 = pr[(size_t)(2 * e2 + 1) * Nn];
      bp.u2[e2] = pk2(p0, p1);
      bq8.u2[e2] = pk2(r0, r1);
    }
    bf16x8 awq = ldfrag(WqBf + (size_t)(dh * 16 + n16) * Cn + kc * 32 + quad * 8);
    bf16x8 awk = ldfrag(WkBf + (size_t)(dh * 16 + n16) * Cn + kc * 32 + quad * 8);
    aq = __builtin_amdgcn_mfma_f32_16x16x32_bf16(awq, bp.v, aq, 0, 0, 0);
    ak = __builtin_amdgcn_mfma_f32_16x16x32_bf16(awk, bq8.v, ak, 0, 0, 0);
    // V: reuse bq8 (pre B-frag) against Wv rows for c-half dh*128
#pragma unroll
    for (int ct = 0; ct < 8; ct++) {
      bf16x8 aw = ldfrag(WvBf + (size_t)(dh * 128 + ct * 16 + n16) * Cn + kc * 32 + quad * 8);
      accv[ct] = __builtin_amdgcn_mfma_f32_16x16x32_bf16(aw, bq8.v, accv[ct], 0, 0, 0);
    }
  }

  // Q/K epilogue (unchanged)
  const float LOG2E = 1.44269504f;
  union { unsigned short s[4]; uint2 u; } oq, ok;
#pragma unroll
  for (int r = 0; r < 4; r++) {
    int d = dh * 16 + quad * 4 + r;
    oq.s[r] = f2bf((aq[r] + bq[d]) * LOG2E);
    ok.s[r] = f2bf(ak[r] + bk[d]);
  }
  *(uint2*)(Qt + ((size_t)b * Nn + i) * Dn + dh * 16 + quad * 4) = oq.u;
  *(uint2*)(Kt + ((size_t)b * Nn + i) * Dn + dh * 16 + quad * 4) = ok.u;

  // V epilogue: bias + bf16 into LDS [c][n-padded], then coalesced copy
#pragma unroll
  for (int ct = 0; ct < 8; ct++) {
#pragma unroll
    for (int r = 0; r < 4; r++) {
      const int c = dh * 128 + ct * 16 + quad * 4 + r;
      sV[c * 40 + isub * 16 + n16] = f2bf(accv[ct][r] + bv[c]);
    }
  }
  __syncthreads();
#pragma unroll
  for (int k = 0; k < 4; k++) {
    const int slot = tid + k * 256;          // 1024 = 256 c x 4 n-octets
    const int c = slot >> 2, seg = slot & 3;
    *(uint4*)(VBf + ((size_t)b * Cn + c) * Nn + i0 + seg * 8) =
        *(const uint4*)(sV + c * 40 + seg * 8);
  }
}

// ---------------------------------------------------------------------------
// Kernel 2: flash attention v9 (unchanged). Async global_load_lds V
// staging single-buffered, DMA covered by S^T/softmax phase; Pl 64-stride
// XOR-swizzled; LDS 40960 -> 4 blocks/CU.
// Grid 1024 = 4b x 64 it(64 i) x 4 js; 256 thr = 4 waves.
// ---------------------------------------------------------------------------
__global__ __launch_bounds__(256, 4) void flash_attn(
    const unsigned short* __restrict__ Qt, const unsigned short* __restrict__ Kt,
    const unsigned short* __restrict__ VBf,
    unsigned short* __restrict__ Opart, float* __restrict__ Lpart)
{
  __shared__ __align__(16) unsigned short sX[256 * 64];  // 32 KB
  __shared__ __align__(16) unsigned short Pl[64 * 64];   // 8 KB (swizzled)

  const int tid = threadIdx.x;
  const int lane = tid & 63, w = tid >> 6;
  const int quad = lane >> 4, n16 = lane & 15;
  const int b = blockIdx.x >> 8;
  const int js = (blockIdx.x >> 6) & 3;
  const int it = blockIdx.x & 63;
  const int i0 = it * 64;
  const int jbase = js * 1024;

  // Q B-frag for wave's own 16-i subtile (S^T: B n=i, k=d)
  const bf16x8 qf = ldfrag(Qt + ((size_t)b * Nn + i0 + w * 16 + n16) * Dn + quad * 8);

  const f32x4 zz = {0.f, 0.f, 0.f, 0.f};
  f32x4 acc[4][4];                       // [i-sub][c-tile within wave's 64 c]
#pragma unroll
  for (int sub = 0; sub < 4; sub++)
#pragma unroll
    for (int ct = 0; ct < 4; ct++) acc[sub][ct] = zz;
  float lrow = 0.f;                      // softmax denom, col i = n16 (dup x4)

  const size_t laneoff = (size_t)(lane >> 3) * Nn + (size_t)(((lane & 7) ^ (lane >> 3)) << 3);
  const unsigned short* preB = VBf + (size_t)b * Cn * Nn + laneoff;
  const int xsw = n16 & 7;
  const int xoff0 = (quad ^ xsw) << 3;
  const int xoff1 = ((4 + quad) ^ xsw) << 3;
  const int psw = (n16 & 7) << 3;        // Pl XOR swizzle (16B units per 8 rows)

  for (int t = 0; t < 16; ++t) {
    const int j0 = jbase + t * 64;
    __syncthreads();                     // sX(t-1)/Pl(t-1) fully consumed
    // async stage V tile 256c x 64j (XOR col swizzle), 8 x 16B per lane
#pragma unroll
    for (int k = 0; k < 8; k++) {
      const int rb = (k * 4 + w) * 8;
      async16(sX + rb * 64 + (lane << 3), preB + (size_t)rb * Nn + j0);
    }
    // S^T = K Q^T for wave's 16 i; K b128 direct from L2-resident Kt
    {
      f32x4 sc[4];
#pragma unroll
      for (int jt = 0; jt < 4; jt++) {
        bf16x8 akf = ldfrag(Kt + ((size_t)b * Nn + j0 + jt * 16 + n16) * Dn + quad * 8);
        sc[jt] = __builtin_amdgcn_mfma_f32_16x16x32_bf16(akf, qf, zz, 0, 0, 0);
      }
      float ps = 0.f;
#pragma unroll
      for (int jt = 0; jt < 4; jt++) {
        float p0 = exp2f(fminf(sc[jt][0], 101.f));
        float p1 = exp2f(fminf(sc[jt][1], 101.f));
        float p2 = exp2f(fminf(sc[jt][2], 101.f));
        float p3 = exp2f(fminf(sc[jt][3], 101.f));
        ps += (p0 + p1) + (p2 + p3);
        union { unsigned int u2[2]; uint2 u; } pk;
        pk.u2[0] = pk2(p0, p1);
        pk.u2[1] = pk2(p2, p3);
        // Pl[i][j], i = w*16+n16, j = jt*16+quad*4..+3 (XOR-swizzled cols)
        *(uint2*)&Pl[(size_t)(w * 16 + n16) * 64 + ((jt * 16 + quad * 4) ^ psw)] = pk.u;
      }
      ps += __shfl_xor(ps, 16);
      ps += __shfl_xor(ps, 32);
      lrow += ps;
    }
    __syncthreads();                     // DMA drained + Pl visible

    // PV(t): U[c][i] += V[c][j] P^T[j][i], 16x16x32 (k = 32 j)
#pragma unroll
    for (int kc = 0; kc < 2; kc++) {
      const int xo = kc ? xoff1 : xoff0;
      bf16x8 pB[4];
#pragma unroll
      for (int sub = 0; sub < 4; sub++)
        pB[sub] = ldfrag(&Pl[(size_t)(sub * 16 + n16) * 64 + ((kc * 32 + quad * 8) ^ psw)]);
#pragma unroll
      for (int ct = 0; ct < 4; ct++) {
        const int crow = w * 64 + ct * 16 + n16;
        bf16x8 av = ldfrag(&sX[crow * 64 + xo]);
        acc[0][ct] = __builtin_amdgcn_mfma_f32_16x16x32_bf16(av, pB[0], acc[0][ct], 0, 0, 0);
        acc[1][ct] = __builtin_amdgcn_mfma_f32_16x16x32_bf16(av, pB[1], acc[1][ct], 0, 0, 0);
        acc[2][ct] = __builtin_amdgcn_mfma_f32_16x16x32_bf16(av, pB[2], acc[2][ct], 0, 0, 0);
        acc[3][ct] = __builtin_amdgcn_mfma_f32_16x16x32_bf16(av, pB[3], acc[3][ct], 0, 0, 0);
      }
    }
  }

  // partial store: O bf16 [js*4+b][i][c], l fp32 [js*4+b][i]
  const size_t pbase = (size_t)(js * 4 + b) * Nn;
  if (quad == 0) Lpart[pbase + i0 + w * 16 + n16] = lrow;
#pragma unroll
  for (int sub = 0; sub < 4; sub++) {
    const int i = i0 + sub * 16 + n16;
#pragma unroll
    for (int ct = 0; ct < 4; ct++) {
      union { unsigned int u2[2]; uint2 u; } pk;
      pk.u2[0] = pk2(acc[sub][ct][0], acc[sub][ct][1]);
      pk.u2[1] = pk2(acc[sub][ct][2], acc[sub][ct][3]);
      *(uint2*)(Opart + (pbase + i) * 256 + w * 64 + ct * 16 + quad * 4) = pk.u;
    }
  }
}

// ---------------------------------------------------------------------------
// Kernel 3: combine v2 — pure streaming merge (no GEMM; Wv applied in
// qkprep). out[b][c][i] = g * (sum_js O[js][i][c]) / l[i] + post[b][c][i].
// Grid 1024 = 4b x 64 i-tiles(64) x 4 c-tiles(64); 256 thr.
// ---------------------------------------------------------------------------
__global__ __launch_bounds__(256) void combine(
    const unsigned short* __restrict__ Opart, const float* __restrict__ Lpart,
    const float* __restrict__ post, const float* __restrict__ gamma,
    float* __restrict__ out)
{
  __shared__ float sT[64 * 65];   // [c][i], stride 65
  __shared__ float sL[64];

  const int tid = threadIdx.x;
  const int b = blockIdx.x >> 8;
  const int rest = blockIdx.x & 255;
  const int i0 = (rest >> 2) * 64;
  const int c0 = (rest & 3) * 64;

  if (tid < 64) {
    float l = 0.f;
#pragma unroll
    for (int js = 0; js < 4; js++) l += Lpart[(size_t)(js * 4 + b) * Nn + i0 + tid];
    sL[tid] = 1.f / l;
  }
  __syncthreads();

  // accumulate 4 partials, normalize, write transposed into sT
#pragma unroll
  for (int pass = 0; pass < 2; pass++) {
    const int il = (tid >> 3) + pass * 32;   // 0..63
    const int c8 = (tid & 7) << 3;           // 0..56
    float a[8] = {0.f, 0.f, 0.f, 0.f, 0.f, 0.f, 0.f, 0.f};
#pragma unroll
    for (int js = 0; js < 4; js++) {
      uint4 uu = *(const uint4*)(Opart + ((size_t)(js * 4 + b) * Nn + i0 + il) * 256 + c0 + c8);
      const unsigned short* us = (const unsigned short*)&uu;
#pragma unroll
      for (int e = 0; e < 8; e++) a[e] += bf2f(us[e]);
    }
    const float inv = sL[il];
#pragma unroll
    for (int e = 0; e < 8; e++) sT[(c8 + e) * 65 + il] = a[e] * inv;
  }
  __syncthreads();

  const float g = gamma[0];
#pragma unroll
  for (int itr = 0; itr < 4; itr++) {
    const int slot = tid + itr * 256;        // 1024 = 64 c x 16 i-quads
    const int cr = slot >> 4, i4 = (slot & 15) << 2;
    const size_t addr = ((size_t)b * Cn + c0 + cr) * Nn + i0 + i4;
    float4 pp = *(const float4*)(post + addr);
    float4 ov;
    ov.x = g * sT[cr * 65 + i4 + 0] + pp.x;
    ov.y = g * sT[cr * 65 + i4 + 1] + pp.y;
    ov.z = g * sT[cr * 65 + i4 + 2] + pp.z;
    ov.w = g * sT[cr * 65 + i4 + 3] + pp.w;
    *(float4*)(out + addr) = ov;
  }
}

extern "C" void kernel_launch(void* const* d_in, const int* in_sizes, int n_in,
                              void* d_out, int out_size, void* d_ws, size_t ws_size,
                              hipStream_t stream) {
  const float* pre   = (const float*)d_in[0];
  const float* post  = (const float*)d_in[1];
  const float* Wq    = (const float*)d_in[2];
  const float* bq    = (const float*)d_in[3];
  const float* Wk    = (const float*)d_in[4];
  const float* bk    = (const float*)d_in[5];
  const float* Wv    = (const float*)d_in[6];
  const float* bv    = (const float*)d_in[7];
  const float* gamma = (const float*)d_in[8];
  float* out = (float*)d_out;

  unsigned short* ws = (unsigned short*)d_ws;
  unsigned short* Qt    = ws;                                   // 512K sh
  unsigned short* Kt    = Qt + (size_t)Bn * Nn * Dn;            // 512K sh
  unsigned short* VBf   = Kt + (size_t)Bn * Nn * Dn;            // 4M sh
  unsigned short* WqBf  = VBf + (size_t)Bn * Cn * Nn;           // 8K sh
  unsigned short* WkBf  = WqBf + Dn * Cn;                       // 8K sh
  unsigned short* WvBf  = WkBf + Dn * Cn;                       // 64K sh
  float* Lpart = (float*)(WvBf + Cn * Cn);                      // 64K fl
  unsigned short* Opart = (unsigned short*)(Lpart + 4 * Bn * Nn);  // 16.7M sh

  wconv<<<40, 256, 0, stream>>>(Wq, Wk, Wv, WqBf, WkBf, WvBf);
  qkprep<<<512, 256, 0, stream>>>(pre, post, WqBf, bq, WkBf, bk, WvBf, bv,
                                  Qt, Kt, VBf);
  flash_attn<<<1024, 256, 0, stream>>>(Qt, Kt, VBf, Opart, Lpart);
  combine<<<1024, 256, 0, stream>>>(Opart, Lpart, post, gamma, out);
}

// Round 7
// 186.850 us; speedup vs baseline: 1.1198x; 1.0005x over previous
//
#include <hip/hip_runtime.h>
#include <hip/hip_bf16.h>

// B=4, C=256, C8=32 (=Dn), H=W=64, N=4096. fp32 I/O; bf16 internal.
#define Bn 4
#define Cn 256
#define Dn 32
#define Nn 4096

typedef __bf16 bf16x8 __attribute__((ext_vector_type(8)));
typedef float f32x4 __attribute__((ext_vector_type(4)));

__device__ __forceinline__ float bf2f(unsigned short u) {
  unsigned int v = ((unsigned int)u) << 16;
  return __builtin_bit_cast(float, v);
}
__device__ __forceinline__ unsigned short f2bf(float f) {
  unsigned int v = __builtin_bit_cast(unsigned int, f);
  v += 0x7FFFu + ((v >> 16) & 1u);  // RNE
  return (unsigned short)(v >> 16);
}
// hardware packed cvt: 2 fp32 -> 2 bf16 (v_cvt_pk_bf16_f32)
__device__ __forceinline__ unsigned int pk2(float a, float b) {
  union { __hip_bfloat162 h; unsigned int u; } x;
  x.h = __float22bfloat162_rn(make_float2(a, b));
  return x.u;
}
__device__ __forceinline__ bf16x8 ldfrag(const unsigned short* p) {
  return __builtin_bit_cast(bf16x8, *(const uint4*)p);
}
__device__ __forceinline__ uint4 pack8(const float* p) {
  float4 a = *(const float4*)p;
  float4 b = *(const float4*)(p + 4);
  union { unsigned int u2[4]; uint4 u; } x;
  x.u2[0] = pk2(a.x, a.y); x.u2[1] = pk2(a.z, a.w);
  x.u2[2] = pk2(b.x, b.y); x.u2[3] = pk2(b.z, b.w);
  return x.u;
}
// async global->LDS, 16 B per lane (lds dest = wave-uniform base + lane*16)
__device__ __forceinline__ void async16(unsigned short* lds, const unsigned short* g) {
  __builtin_amdgcn_global_load_lds(
      (const __attribute__((address_space(1))) unsigned int*)g,
      (__attribute__((address_space(3))) unsigned int*)lds, 16, 0, 0);
}

// ---------------------------------------------------------------------------
// Kernel 0: wconv — convert Wq/Wk/Wv fp32 -> bf16 ONCE.
// ---------------------------------------------------------------------------
__global__ __launch_bounds__(256) void wconv(
    const float* __restrict__ Wq, const float* __restrict__ Wk,
    const float* __restrict__ Wv,
    unsigned short* __restrict__ WqBf, unsigned short* __restrict__ WkBf,
    unsigned short* __restrict__ WvBf)
{
  const size_t base = ((size_t)blockIdx.x * 256 + threadIdx.x) * 8;
  if (base < 8192) {
    *(uint4*)(WqBf + base) = pack8(Wq + base);
  } else if (base < 16384) {
    *(uint4*)(WkBf + base - 8192) = pack8(Wk + base - 8192);
  } else {
    *(uint4*)(WvBf + base - 16384) = pack8(Wv + base - 16384);
  }
}

// ---------------------------------------------------------------------------
// Kernel 1: qkprep v4 — fused Q/K/V projections (unchanged from R6).
// ---------------------------------------------------------------------------
__global__ __launch_bounds__(256) void qkprep(
    const float* __restrict__ pre, const float* __restrict__ post,
    const unsigned short* __restrict__ WqBf, const float* __restrict__ bq,
    const unsigned short* __restrict__ WkBf, const float* __restrict__ bk,
    const unsigned short* __restrict__ WvBf, const float* __restrict__ bv,
    unsigned short* __restrict__ Qt, unsigned short* __restrict__ Kt,
    unsigned short* __restrict__ VBf)
{
  __shared__ __align__(16) unsigned short sV[256 * 40];  // 20 KB

  const int tid = threadIdx.x;
  const int lane = tid & 63, w = tid >> 6;
  const int quad = lane >> 4, n16 = lane & 15;
  const int b = blockIdx.x >> 7;
  const int i0 = (blockIdx.x & 127) << 5;
  const int isub = w & 1, dh = w >> 1;
  const int i = i0 + isub * 16 + n16;

  const f32x4 zz = {0.f, 0.f, 0.f, 0.f};
  f32x4 aq = zz, ak = zz;
  f32x4 accv[8];
#pragma unroll
  for (int ct = 0; ct < 8; ct++) accv[ct] = zz;

  const float* postB = post + (size_t)b * Cn * Nn + i;
  const float* preB  = pre  + (size_t)b * Cn * Nn + i;

#pragma unroll
  for (int kc = 0; kc < 8; kc++) {
    const int c0 = kc * 32 + quad * 8;
    const float* pp = postB + (size_t)c0 * Nn;
    const float* pr = preB + (size_t)c0 * Nn;
    union { unsigned int u2[4]; bf16x8 v; } bp, bq8;
#pragma unroll
    for (int e2 = 0; e2 < 4; e2++) {
      float p0 = pp[(size_t)(2 * e2) * Nn], p1 = pp[(size_t)(2 * e2 + 1) * Nn];
      float r0 = pr[(size_t)(2 * e2) * Nn], r1 = pr[(size_t)(2 * e2 + 1) * Nn];
      bp.u2[e2] = pk2(p0, p1);
      bq8.u2[e2] = pk2(r0, r1);
    }
    bf16x8 awq = ldfrag(WqBf + (size_t)(dh * 16 + n16) * Cn + kc * 32 + quad * 8);
    bf16x8 awk = ldfrag(WkBf + (size_t)(dh * 16 + n16) * Cn + kc * 32 + quad * 8);
    aq = __builtin_amdgcn_mfma_f32_16x16x32_bf16(awq, bp.v, aq, 0, 0, 0);
    ak = __builtin_amdgcn_mfma_f32_16x16x32_bf16(awk, bq8.v, ak, 0, 0, 0);
#pragma unroll
    for (int ct = 0; ct < 8; ct++) {
      bf16x8 aw = ldfrag(WvBf + (size_t)(dh * 128 + ct * 16 + n16) * Cn + kc * 32 + quad * 8);
      accv[ct] = __builtin_amdgcn_mfma_f32_16x16x32_bf16(aw, bq8.v, accv[ct], 0, 0, 0);
    }
  }

  const float LOG2E = 1.44269504f;
  union { unsigned short s[4]; uint2 u; } oq, ok;
#pragma unroll
  for (int r = 0; r < 4; r++) {
    int d = dh * 16 + quad * 4 + r;
    oq.s[r] = f2bf((aq[r] + bq[d]) * LOG2E);
    ok.s[r] = f2bf(ak[r] + bk[d]);
  }
  *(uint2*)(Qt + ((size_t)b * Nn + i) * Dn + dh * 16 + quad * 4) = oq.u;
  *(uint2*)(Kt + ((size_t)b * Nn + i) * Dn + dh * 16 + quad * 4) = ok.u;

#pragma unroll
  for (int ct = 0; ct < 8; ct++) {
#pragma unroll
    for (int r = 0; r < 4; r++) {
      const int c = dh * 128 + ct * 16 + quad * 4 + r;
      sV[c * 40 + isub * 16 + n16] = f2bf(accv[ct][r] + bv[c]);
    }
  }
  __syncthreads();
#pragma unroll
  for (int k = 0; k < 4; k++) {
    const int slot = tid + k * 256;          // 1024 = 256 c x 4 n-octets
    const int c = slot >> 2, seg = slot & 3;
    *(uint4*)(VBf + ((size_t)b * Cn + c) * Nn + i0 + seg * 8) =
        *(const uint4*)(sV + c * 40 + seg * 8);
  }
}

// ---------------------------------------------------------------------------
// Kernel 2: flash attention v10 — counted-vmcnt ping-pong. j-tile 32,
// 32 iters. Per iter: __syncthreads (drains DMA(t)) -> K(t+1) loads THEN
// DMA(t+1) into sX[nxt] (issue order => consuming K waits only vmcnt(4),
// keeping DMA in flight) -> PV(t) -> raw s_barrier + lgkmcnt(0) (Pl
// protection, NO vmem drain) -> S^T/softmax(t+1) -> Pl. DMA cover = full
// iteration. LDS: sX[2][256*32] 32KB + Pl[64*32] 4KB = 36864 B -> 4 blk/CU.
// Pl + sX use XOR-16B-unit swizzle (unit ^= row&3) -> <=4-way conflicts.
// Grid 1024 = 4b x 64 it(64 i) x 4 js; 256 thr = 4 waves.
// ---------------------------------------------------------------------------
__global__ __launch_bounds__(256, 4) void flash_attn(
    const unsigned short* __restrict__ Qt, const unsigned short* __restrict__ Kt,
    const unsigned short* __restrict__ VBf,
    unsigned short* __restrict__ Opart, float* __restrict__ Lpart)
{
  __shared__ __align__(16) unsigned short sX[2][256 * 32];  // 32 KB
  __shared__ __align__(16) unsigned short Pl[64 * 32];      // 4 KB

  const int tid = threadIdx.x;
  const int lane = tid & 63, w = tid >> 6;
  const int quad = lane >> 4, n16 = lane & 15;
  const int b = blockIdx.x >> 8;
  const int js = (blockIdx.x >> 6) & 3;
  const int it = blockIdx.x & 63;
  const int i0 = it * 64;
  const int jbase = js * 1024;

  // Q B-frag for wave's own 16-i subtile (S^T: B n=i, k=d)
  const bf16x8 qf = ldfrag(Qt + ((size_t)b * Nn + i0 + w * 16 + n16) * Dn + quad * 8);

  const f32x4 zz = {0.f, 0.f, 0.f, 0.f};
  f32x4 acc[4][4];                       // [i-sub][c-tile within wave's 64 c]
#pragma unroll
  for (int sub = 0; sub < 4; sub++)
#pragma unroll
    for (int ct = 0; ct < 4; ct++) acc[sub][ct] = zz;
  float lrow = 0.f;

  // --- static address helpers ---
  const int x3 = n16 & 3;
  const int xrd = (quad ^ x3) << 3;              // 16B-unit XOR for Pl/sX reads
  const int row32 = (w * 16 + n16) * 32;
  const int plw0 = row32 + ((((quad >> 1) + 0) ^ x3) << 3) + ((quad & 1) << 2);
  const int plw1 = row32 + ((((quad >> 1) + 2) ^ x3) << 3) + ((quad & 1) << 2);
  const unsigned short* pK = Kt + ((size_t)b * Nn + n16) * Dn + quad * 8;
  const unsigned short* vb = VBf + (size_t)b * Cn * Nn;
  // DMA source: LDS[row][unit u] <- V[row][chunk u ^ (row&3)]
  size_t dmaoff[4];
#pragma unroll
  for (int k = 0; k < 4; k++) {
    const int row = (k * 4 + w) * 16 + (lane >> 2);
    dmaoff[k] = (size_t)row * Nn + (size_t)(((lane & 3) ^ ((lane >> 2) & 3)) << 3);
  }

#define S_PHASE(A0, A1, JT0)                                                  \
  {                                                                           \
    f32x4 sc0 = __builtin_amdgcn_mfma_f32_16x16x32_bf16((A0), qf, zz, 0, 0, 0); \
    f32x4 sc1 = __builtin_amdgcn_mfma_f32_16x16x32_bf16((A1), qf, zz, 0, 0, 0); \
    float q0 = exp2f(fminf(sc0[0], 101.f)), q1 = exp2f(fminf(sc0[1], 101.f)); \
    float q2 = exp2f(fminf(sc0[2], 101.f)), q3 = exp2f(fminf(sc0[3], 101.f)); \
    float q4 = exp2f(fminf(sc1[0], 101.f)), q5 = exp2f(fminf(sc1[1], 101.f)); \
    float q6 = exp2f(fminf(sc1[2], 101.f)), q7 = exp2f(fminf(sc1[3], 101.f)); \
    union { unsigned int u2[2]; uint2 u; } pka, pkb;                          \
    pka.u2[0] = pk2(q0, q1); pka.u2[1] = pk2(q2, q3);                         \
    pkb.u2[0] = pk2(q4, q5); pkb.u2[1] = pk2(q6, q7);                         \
    *(uint2*)&Pl[plw0] = pka.u;                                               \
    *(uint2*)&Pl[plw1] = pkb.u;                                               \
    float ps = (q0 + q1) + (q2 + q3) + (q4 + q5) + (q6 + q7);                 \
    ps += __shfl_xor(ps, 16);                                                 \
    ps += __shfl_xor(ps, 32);                                                 \
    lrow += ps;                                                               \
  }

  // --- prologue: K(0), DMA(0) -> buf0, S-phase(0) ---
  bf16x8 akf0 = ldfrag(pK + (size_t)jbase * Dn);
  bf16x8 akf1 = ldfrag(pK + (size_t)(jbase + 16) * Dn);
  __builtin_amdgcn_sched_barrier(0);
#pragma unroll
  for (int k = 0; k < 4; k++)
    async16(&sX[0][(k * 4 + w) * 512], vb + dmaoff[k] + jbase);
  __builtin_amdgcn_sched_barrier(0);
  S_PHASE(akf0, akf1, 0)

  for (int t = 0; t < 32; ++t) {
    const int cur = t & 1;
    __syncthreads();                     // drains DMA(t); Pl(t) visible
    if (t < 31) {
      const int j0n = jbase + (t + 1) * 32;
      akf0 = ldfrag(pK + (size_t)j0n * Dn);
      akf1 = ldfrag(pK + (size_t)(j0n + 16) * Dn);
      __builtin_amdgcn_sched_barrier(0); // pin K before DMA (vmcnt trick)
#pragma unroll
      for (int k = 0; k < 4; k++)
        async16(&sX[cur ^ 1][(k * 4 + w) * 512], vb + dmaoff[k] + j0n);
      __builtin_amdgcn_sched_barrier(0);
    }
    // PV(t): U[c][i] += V[c][j] P^T[j][i], one 16x16x32 step (k = 32 j)
    {
      const unsigned short* sXc = sX[cur];
      bf16x8 pB[4];
#pragma unroll
      for (int sub = 0; sub < 4; sub++)
        pB[sub] = ldfrag(&Pl[(sub * 16 + n16) * 32 + xrd]);
#pragma unroll
      for (int ct = 0; ct < 4; ct++) {
        bf16x8 av = ldfrag(&sXc[(w * 64 + ct * 16 + n16) * 32 + xrd]);
        acc[0][ct] = __builtin_amdgcn_mfma_f32_16x16x32_bf16(av, pB[0], acc[0][ct], 0, 0, 0);
        acc[1][ct] = __builtin_amdgcn_mfma_f32_16x16x32_bf16(av, pB[1], acc[1][ct], 0, 0, 0);
        acc[2][ct] = __builtin_amdgcn_mfma_f32_16x16x32_bf16(av, pB[2], acc[2][ct], 0, 0, 0);
        acc[3][ct] = __builtin_amdgcn_mfma_f32_16x16x32_bf16(av, pB[3], acc[3][ct], 0, 0, 0);
      }
    }
    if (t < 31) {
      // raw barrier: Pl rewrite safe, DMA(t+1) stays in flight (no vm drain)
      asm volatile("s_waitcnt lgkmcnt(0)" ::: "memory");
      __builtin_amdgcn_s_barrier();
      __builtin_amdgcn_sched_barrier(0);
      S_PHASE(akf0, akf1, t + 1)        // consumes K -> vmcnt(4) only
    }
  }
#undef S_PHASE

  // partial store: O bf16 [js*4+b][i][c], l fp32 [js*4+b][i]
  const size_t pbase = (size_t)(js * 4 + b) * Nn;
  if (quad == 0) Lpart[pbase + i0 + w * 16 + n16] = lrow;
#pragma unroll
  for (int sub = 0; sub < 4; sub++) {
    const int i = i0 + sub * 16 + n16;
#pragma unroll
    for (int ct = 0; ct < 4; ct++) {
      union { unsigned int u2[2]; uint2 u; } pk;
      pk.u2[0] = pk2(acc[sub][ct][0], acc[sub][ct][1]);
      pk.u2[1] = pk2(acc[sub][ct][2], acc[sub][ct][3]);
      *(uint2*)(Opart + (pbase + i) * 256 + w * 64 + ct * 16 + quad * 4) = pk.u;
    }
  }
}

// ---------------------------------------------------------------------------
// Kernel 3: combine v2 — pure streaming merge (unchanged from R6).
// ---------------------------------------------------------------------------
__global__ __launch_bounds__(256) void combine(
    const unsigned short* __restrict__ Opart, const float* __restrict__ Lpart,
    const float* __restrict__ post, const float* __restrict__ gamma,
    float* __restrict__ out)
{
  __shared__ float sT[64 * 65];   // [c][i], stride 65
  __shared__ float sL[64];

  const int tid = threadIdx.x;
  const int b = blockIdx.x >> 8;
  const int rest = blockIdx.x & 255;
  const int i0 = (rest >> 2) * 64;
  const int c0 = (rest & 3) * 64;

  if (tid < 64) {
    float l = 0.f;
#pragma unroll
    for (int js = 0; js < 4; js++) l += Lpart[(size_t)(js * 4 + b) * Nn + i0 + tid];
    sL[tid] = 1.f / l;
  }
  __syncthreads();

#pragma unroll
  for (int pass = 0; pass < 2; pass++) {
    const int il = (tid >> 3) + pass * 32;   // 0..63
    const int c8 = (tid & 7) << 3;           // 0..56
    float a[8] = {0.f, 0.f, 0.f, 0.f, 0.f, 0.f, 0.f, 0.f};
#pragma unroll
    for (int js = 0; js < 4; js++) {
      uint4 uu = *(const uint4*)(Opart + ((size_t)(js * 4 + b) * Nn + i0 + il) * 256 + c0 + c8);
      const unsigned short* us = (const unsigned short*)&uu;
#pragma unroll
      for (int e = 0; e < 8; e++) a[e] += bf2f(us[e]);
    }
    const float inv = sL[il];
#pragma unroll
    for (int e = 0; e < 8; e++) sT[(c8 + e) * 65 + il] = a[e] * inv;
  }
  __syncthreads();

  const float g = gamma[0];
#pragma unroll
  for (int itr = 0; itr < 4; itr++) {
    const int slot = tid + itr * 256;        // 1024 = 64 c x 16 i-quads
    const int cr = slot >> 4, i4 = (slot & 15) << 2;
    const size_t addr = ((size_t)b * Cn + c0 + cr) * Nn + i0 + i4;
    float4 pp = *(const float4*)(post + addr);
    float4 ov;
    ov.x = g * sT[cr * 65 + i4 + 0] + pp.x;
    ov.y = g * sT[cr * 65 + i4 + 1] + pp.y;
    ov.z = g * sT[cr * 65 + i4 + 2] + pp.z;
    ov.w = g * sT[cr * 65 + i4 + 3] + pp.w;
    *(float4*)(out + addr) = ov;
  }
}

extern "C" void kernel_launch(void* const* d_in, const int* in_sizes, int n_in,
                              void* d_out, int out_size, void* d_ws, size_t ws_size,
                              hipStream_t stream) {
  const float* pre   = (const float*)d_in[0];
  const float* post  = (const float*)d_in[1];
  const float* Wq    = (const float*)d_in[2];
  const float* bq    = (const float*)d_in[3];
  const float* Wk    = (const float*)d_in[4];
  const float* bk    = (const float*)d_in[5];
  const float* Wv    = (const float*)d_in[6];
  const float* bv    = (const float*)d_in[7];
  const float* gamma = (const float*)d_in[8];
  float* out = (float*)d_out;

  unsigned short* ws = (unsigned short*)d_ws;
  unsigned short* Qt    = ws;                                   // 512K sh
  unsigned short* Kt    = Qt + (size_t)Bn * Nn * Dn;            // 512K sh
  unsigned short* VBf   = Kt + (size_t)Bn * Nn * Dn;            // 4M sh
  unsigned short* WqBf  = VBf + (size_t)Bn * Cn * Nn;           // 8K sh
  unsigned short* WkBf  = WqBf + Dn * Cn;                       // 8K sh
  unsigned short* WvBf  = WkBf + Dn * Cn;                       // 64K sh
  float* Lpart = (float*)(WvBf + Cn * Cn);                      // 64K fl
  unsigned short* Opart = (unsigned short*)(Lpart + 4 * Bn * Nn);  // 16.7M sh

  wconv<<<40, 256, 0, stream>>>(Wq, Wk, Wv, WqBf, WkBf, WvBf);
  qkprep<<<512, 256, 0, stream>>>(pre, post, WqBf, bq, WkBf, bk, WvBf, bv,
                                  Qt, Kt, VBf);
  flash_attn<<<1024, 256, 0, stream>>>(Qt, Kt, VBf, Opart, Lpart);
  combine<<<1024, 256, 0, stream>>>(Opart, Lpart, post, gamma, out);
}